// Round 1
// baseline (96.262 us; speedup 1.0000x reference)
//
#include <hip/hip_runtime.h>
#include <math.h>

// Problem constants
#define BB     64
#define SS     8192
#define DD     64
#define NBINS  256
#define TPB    1024          // 16 waves
#define GROUPS 8             // bin-groups per batch -> grid = 64*8 = 512 blocks
#define GBINS  (NBINS / GROUPS)   // 32 bins owned per block
#define SEG    128           // payload slots per bin (mean 32, +17 sigma; pow2 for shift addressing)
#define CAPT   (GBINS * SEG) // 4096 payload slots (32 KiB LDS total payload)

// Round-10 structure: single-pass stage+scatter into FIXED per-bin segments.
//  - no count pass, no prefix scan, no payload zero-init: 2 barriers total (was 4)
//  - one LDS atomic per kept token (was two: count + cursor)
//  - counts recovered from cursors; only written slots are ever read
//    (masked remainder lanes read slot `base`, which is written whenever cnt>=1,
//     and the loop body is skipped entirely when cnt==0 -> stale-LDS safe)
//  - accumulate: 16 tokens/iter -> 4 independent row-gathers in flight per lane
//  - T/X staged as float4/int4 (4 VMEM instructions instead of 16)
__global__ __launch_bounds__(TPB, 8) void embedder_fused_kernel(
    const float* __restrict__ T,
    const int*   __restrict__ X_ids,
    const float* __restrict__ embedX,
    const float* __restrict__ embedW,
    float4*      __restrict__ out4)      // [BB][NBINS][16]
{
    __shared__ int      l_sid[CAPT];     // token ids   (16 KiB)
    __shared__ float    l_sw[CAPT];      // token weights (16 KiB)
    __shared__ unsigned l_cur[GBINS];    // absolute scatter cursors

    const int blk    = blockIdx.x;
    const int b      = blk >> 3;
    const int bin_lo = (blk & 7) * GBINS;
    const int tid    = threadIdx.x;
    const int lane   = tid & 63;
    const int wv     = tid >> 6;         // 0..15

    // ---- cursor init: absolute base of each bin's fixed segment ----
    if (tid < GBINS) l_cur[tid] = (unsigned)(tid << 7);   // tid * SEG
    __syncthreads();

    // ---- fused stage + scatter: one pass, 8 tokens/thread, vector loads ----
    {
        const float4* __restrict__ T4 = (const float4*)(T     + (size_t)b * SS);
        const int4*   __restrict__ X4 = (const int4*)  (X_ids + (size_t)b * SS);
        const float4 ta = T4[tid * 2];
        const float4 tb = T4[tid * 2 + 1];
        const int4   xa = X4[tid * 2];
        const int4   xb = X4[tid * 2 + 1];
        const float tt[8] = { ta.x, ta.y, ta.z, ta.w, tb.x, tb.y, tb.z, tb.w };
        const int   ii[8] = { xa.x, xa.y, xa.z, xa.w, xb.x, xb.y, xb.z, xb.w };

        #pragma unroll
        for (int k = 0; k < 8; ++k) {
            const float t  = tt[k];
            const int   id = ii[k];
            const int bin  = (t < 256.0f) ? (int)t : NBINS;   // NBINS = dummy
            const unsigned rel = (unsigned)(bin - bin_lo);
            if (rel < (unsigned)GBINS) {
                const float w = __expf(embedW[id]);
                const unsigned pos = atomicAdd(&l_cur[rel], 1u);
                if (pos < ((rel + 1u) << 7)) {                // overflow guard (never in practice)
                    l_sid[pos] = id;
                    l_sw[pos]  = w;
                }
            }
        }
    }
    __syncthreads();

    // ---- accumulate: wave wv owns bins {2wv, 2wv+1}; 16 tokens/iter ----
    const int q   = lane & 15;           // which float4 of the 64-float row
    const int sub = lane >> 4;           // token sub-group 0..3
    const float4* __restrict__ ex4 = (const float4*)embedX;

    #pragma unroll
    for (int c = 0; c < 2; ++c) {
        const int bin  = wv * 2 + c;
        const int base = bin << 7;       // bin * SEG
        int cnt = (int)l_cur[bin] - base;
        cnt = (cnt > SEG) ? SEG : cnt;   // clamp to written slots

        float4 acc = make_float4(0.f, 0.f, 0.f, 0.f);

        for (int tb = 0; tb < cnt; tb += 16) {
            #pragma unroll
            for (int g = 0; g < 4; ++g) {       // 4 independent gathers in flight
                const int  tk  = tb + g * 4 + sub;
                const bool ok  = (tk < cnt);
                const int  idx = base + (ok ? tk : 0);   // slot 0 written when cnt>=1
                const int   s  = l_sid[idx];             // 16 q-lanes broadcast-read
                const float w  = ok ? l_sw[idx] : 0.0f;
                const float4 v = ex4[(size_t)s * 16 + q];
                acc.x += w * v.x;  acc.y += w * v.y;
                acc.z += w * v.z;  acc.w += w * v.w;
            }
        }

        // fold the 4 token-subgroups (lanes xor 16, then xor 32)
        acc.x += __shfl_xor(acc.x, 16, 64); acc.y += __shfl_xor(acc.y, 16, 64);
        acc.z += __shfl_xor(acc.z, 16, 64); acc.w += __shfl_xor(acc.w, 16, 64);
        acc.x += __shfl_xor(acc.x, 32, 64); acc.y += __shfl_xor(acc.y, 32, 64);
        acc.z += __shfl_xor(acc.z, 32, 64); acc.w += __shfl_xor(acc.w, 32, 64);

        if (sub == 0) {
            const float inv = 1.0f / ((float)cnt + 1e-6f);
            acc.x *= inv; acc.y *= inv; acc.z *= inv; acc.w *= inv;
            out4[((size_t)b * NBINS + bin_lo + bin) * 16 + q] = acc;  // 256B/bin
        }
    }
}

extern "C" void kernel_launch(void* const* d_in, const int* in_sizes, int n_in,
                              void* d_out, int out_size, void* d_ws, size_t ws_size,
                              hipStream_t stream) {
    const float* T      = (const float*)d_in[0];
    const int*   X_ids  = (const int*)  d_in[1];
    const float* embedX = (const float*)d_in[2];
    const float* embedW = (const float*)d_in[3];
    float4* out4 = (float4*)d_out;

    embedder_fused_kernel<<<BB * GROUPS, TPB, 0, stream>>>(
        T, X_ids, embedX, embedW, out4);
}